// Round 22
// baseline (210.970 us; speedup 1.0000x reference)
//
#include <hip/hip_runtime.h>
#include <hip/hip_bf16.h>

#define DEVI static __device__ __forceinline__

typedef __attribute__((ext_vector_type(8))) _Float16 f16x8;
typedef __attribute__((ext_vector_type(2))) __fp16 fp16v2;   // cvt_pkrtz return type
typedef __attribute__((ext_vector_type(4))) float f32x4;
typedef __attribute__((ext_vector_type(16))) float f32x16;
typedef __attribute__((ext_vector_type(8))) unsigned short u16x8;
typedef __attribute__((ext_vector_type(4))) unsigned int u32x4;
typedef __attribute__((ext_vector_type(2))) unsigned int u32x2;
typedef unsigned short u16;

constexpr int NE = 1024;   // n_embd
constexpr int NH = 16;     // heads
constexpr int HD = 64;     // head dim
constexpr int SB = 4;      // batch
constexpr int SS = 2048;   // seq
constexpr int MR = SB * SS; // 8192 rows

DEVI u16 f2h(float f) {
  union { _Float16 h; u16 u; } x;
  x.h = (_Float16)f;
  return x.u;
}

DEVI unsigned pk2(float lo, float hi) {
  union { fp16v2 h2; unsigned u; } cv;
  cv.h2 = __builtin_amdgcn_cvt_pkrtz(lo, hi);
  return cv.u;
}

DEVI void gload_lds16(const void* g, void* l) {
  __builtin_amdgcn_global_load_lds(
      (const __attribute__((address_space(1))) unsigned int*)g,
      (__attribute__((address_space(3))) unsigned int*)l, 16, 0, 0);
}

// ---------------- x fp32 -> fp16 ----------------
__global__ void k_cvt_x(const float* __restrict__ x, u16* __restrict__ xb) {
  size_t i = (size_t)blockIdx.x * 256 + threadIdx.x;
  const f32x4* s4 = (const f32x4*)x;
  f32x4 a = s4[2 * i], c = s4[2 * i + 1];
  u16x8 o;
  o[0] = f2h(a[0]); o[1] = f2h(a[1]); o[2] = f2h(a[2]); o[3] = f2h(a[3]);
  o[4] = f2h(c[0]); o[5] = f2h(c[1]); o[6] = f2h(c[2]); o[7] = f2h(c[3]);
  ((u16x8*)xb)[i] = o;
}

// ---------------- W [K][N] fp32 -> W^T [N][K] fp16 (4 weights) ----------------
__global__ void k_wt(const float* __restrict__ W0, const float* __restrict__ W1,
                     const float* __restrict__ W2, const float* __restrict__ W3,
                     u16* __restrict__ WT) {
  __shared__ float tile[64][65];
  const float* W = (blockIdx.z == 0) ? W0 : (blockIdx.z == 1) ? W1 : (blockIdx.z == 2) ? W2 : W3;
  u16* T = WT + (size_t)blockIdx.z * NE * NE;
  int tid = threadIdx.x, c = tid & 63, rr = tid >> 6;
  int ti = blockIdx.y * 64, tj = blockIdx.x * 64;
#pragma unroll
  for (int p = 0; p < 16; p++) {
    int r = p * 4 + rr;
    tile[r][c] = W[(size_t)(ti + r) * NE + tj + c];
  }
  __syncthreads();
#pragma unroll
  for (int p = 0; p < 16; p++) {
    int r = p * 4 + rr;
    T[(size_t)(tj + r) * NE + ti + c] = f2h(tile[c][r]);
  }
}

// ---------------- GEMM: C[M][1024] = A[M][1024] @ (BT[1024][1024])^T + bias ----------------
template <int MODE>
__global__ __launch_bounds__(256) void k_gemm(const u16* __restrict__ A,
                                              const u16* __restrict__ BT,
                                              const float* __restrict__ bias,
                                              void* __restrict__ outp) {
  __shared__ __align__(16) u16 lA[128 * 64];
  __shared__ __align__(16) u16 lB[128 * 64];
  const int tid = threadIdx.x;
  const int wave = tid >> 6, lane = tid & 63;
  const int wr = wave >> 1, wc = wave & 1;
  const int fr = lane & 15, fg = lane >> 4;
  const int srow = lane >> 3;
  const int scol = ((lane & 7) ^ srow) * 8;
  const int mb = blockIdx.x, nb = blockIdx.y;
  f32x4 acc[4][4] = {};
  for (int kt = 0; kt < NE / 64; ++kt) {
#pragma unroll
    for (int p = 0; p < 4; p++) {
      int rb = wave * 32 + p * 8;
      gload_lds16(A + (size_t)(mb * 128 + rb + srow) * NE + kt * 64 + scol, lA + rb * 64);
      gload_lds16(BT + (size_t)(nb * 128 + rb + srow) * NE + kt * 64 + scol, lB + rb * 64);
    }
    __syncthreads();
#pragma unroll
    for (int kd = 0; kd < 2; ++kd) {
      f16x8 af[4], bg[4];
#pragma unroll
      for (int mi = 0; mi < 4; mi++) {
        int row = wr * 64 + mi * 16 + fr;
        af[mi] = *(const f16x8*)((const char*)lA + row * 128 + ((kd * 64 + fg * 16) ^ ((row & 7) << 4)));
      }
#pragma unroll
      for (int nj = 0; nj < 4; nj++) {
        int row = wc * 64 + nj * 16 + fr;
        bg[nj] = *(const f16x8*)((const char*)lB + row * 128 + ((kd * 64 + fg * 16) ^ ((row & 7) << 4)));
      }
#pragma unroll
      for (int mi = 0; mi < 4; mi++)
#pragma unroll
        for (int nj = 0; nj < 4; nj++)
          acc[mi][nj] = __builtin_amdgcn_mfma_f32_16x16x32_f16(af[mi], bg[nj], acc[mi][nj], 0, 0, 0);
    }
    __syncthreads();
  }
  float bv[4];
#pragma unroll
  for (int nj = 0; nj < 4; nj++) bv[nj] = bias[nb * 128 + wc * 64 + nj * 16 + fr];
#pragma unroll
  for (int mi = 0; mi < 4; mi++)
#pragma unroll
    for (int nj = 0; nj < 4; nj++)
#pragma unroll
      for (int r = 0; r < 4; r++) {
        int row = mb * 128 + wr * 64 + mi * 16 + fg * 4 + r;
        int col = nb * 128 + wc * 64 + nj * 16 + fr;
        float v = acc[mi][nj][r] + bv[nj];
        if constexpr (MODE == 2) {
          ((float*)outp)[(size_t)row * NE + col] = v;
        } else if constexpr (MODE == 0) {
          ((u16*)outp)[(size_t)row * NE + col] = f2h(v);
        } else {
          int b = row >> 11, s = row & (SS - 1);
          int h = col >> 6, d = col & 63;
          ((u16*)outp)[(((size_t)(b * NH + h) * HD + d) << 11) | (size_t)s] = f2h(v);
        }
      }
}

// ---------------- flash attention: 16-wave blocks, 2 tiles per barrier (4-buf) ----------------
// grid 256 (XCD-swizzled), 1024 threads (16 waves x 32 q-rows = 512 q-rows/block).
// Q,K: [B][S][H*D] fp16. VT: [B][H][D][S] fp16. AO: [B][S][H*D] fp16.
__global__ __launch_bounds__(1024) void k_attn(const u16* __restrict__ Q, const u16* __restrict__ K,
                                               const u16* __restrict__ VT, u16* __restrict__ AO) {
  // staging 4K+4V buffers (64 KB) and epilogue (72 KB) alias; epilogue after loop only.
  __shared__ __align__(16) char smem_raw[73728];
  u16* smem = (u16*)smem_raw;                    // [K0..K3 | V0..V3], each 64x64 fp16
  const int tid = threadIdx.x, wave = tid >> 6, lane = tid & 63;
  const int q32 = lane & 31, hh = lane >> 5;
  const int srow = lane >> 3;
  const int scol = ((lane & 7) ^ srow) * 8;
  // XCD-aware decode: 4 q-blocks (512 rows each) of one (b,h) stay on one XCD
  const int bid = blockIdx.x;
  const int xcd = bid & 7, idx = bid >> 3;       // idx in [0,32)
  const int g = xcd * 8 + (idx >> 2);            // (b,h) group in [0,64)
  const int qb = (idx & 3) * 512;
  const int b = g >> 4, h = g & 15;
  const u16* Kg = K + (size_t)(b * SS) * NE + h * HD;
  const u16* Vg = VT + (size_t)(b * NH + h) * HD * SS;
  const u16* Qp = Q + (size_t)(b * SS + qb + wave * 32 + q32) * NE + h * HD;
  f16x8 qf[4];
#pragma unroll
  for (int m = 0; m < 4; m++) qf[m] = *(const f16x8*)(Qp + m * 16 + hh * 8);
  f32x16 oacc[2] = {};
  float m_s = -1e30f, l_s = 0.f;
  const float SC = 8.0f * 1.44269504088896340736f;

  // 16 waves split the staging: waves 0-7 stage K rows [w*8,w*8+8), waves 8-15 stage V
  auto STAGE = [&](int kt2, int bufi) {
    if (wave < 8) {
      u16* lk = smem + bufi * 4096;
      int rb = wave * 8;
      gload_lds16(Kg + (size_t)(kt2 * 64 + rb + srow) * NE + scol, lk + rb * 64);
    } else {
      u16* lv = smem + 16384 + bufi * 4096;
      int rb = (wave - 8) * 8;
      gload_lds16(Vg + (size_t)(rb + srow) * SS + kt2 * 64 + scol, lv + rb * 64);
    }
  };

  auto QK = [&](int bufi, f32x16* s) {
    const u16* lk = smem + bufi * 4096;
#pragma unroll
    for (int kt32 = 0; kt32 < 2; kt32++) {
      f32x16 z = {};
      int row = kt32 * 32 + q32;
      __builtin_amdgcn_s_setprio(1);
#pragma unroll
      for (int m = 0; m < 4; m++) {
        f16x8 kf = *(const f16x8*)((const char*)lk + row * 128 + ((m * 32 + hh * 16) ^ ((row & 7) << 4)));
        z = __builtin_amdgcn_mfma_f32_32x32x16_f16(kf, qf[m], z, 0, 0, 0);
      }
      __builtin_amdgcn_s_setprio(0);
      s[kt32] = z;
    }
  };

  auto SMPV = [&](int bufiV, f32x16* s) {
    const u16* lv = smem + 16384 + bufiV * 4096;
    float a[16];
#pragma unroll
    for (int r = 0; r < 16; r++) a[r] = fmaxf(s[0][r], s[1][r]);
#pragma unroll
    for (int st = 8; st > 0; st >>= 1)
#pragma unroll
      for (int r = 0; r < st; r++) a[r] = fmaxf(a[r], a[r + st]);
    float mx = a[0] * SC;
    mx = fmaxf(mx, __shfl_xor(mx, 32));
    float mo = m_s, mu = mo;
    if (!__all(mx <= mo + 8.f)) {
      float nm = fmaxf(mo, mx);
      float fs = __builtin_amdgcn_exp2f(mo - nm);
      m_s = nm; mu = nm; l_s *= fs;
#pragma unroll
      for (int d2 = 0; d2 < 2; d2++)
#pragma unroll
        for (int r = 0; r < 16; r++) oacc[d2][r] *= fs;
    }
    float p[2][16];
#pragma unroll
    for (int kt32 = 0; kt32 < 2; kt32++)
#pragma unroll
      for (int r = 0; r < 16; r++)
        p[kt32][r] = __builtin_amdgcn_exp2f(s[kt32][r] * SC - mu);
    float t[16];
#pragma unroll
    for (int r = 0; r < 16; r++) t[r] = p[0][r] + p[1][r];
#pragma unroll
    for (int st = 8; st > 0; st >>= 1)
#pragma unroll
      for (int r = 0; r < st; r++) t[r] += t[r + st];
    float rs = t[0];
    rs += __shfl_xor(rs, 32);
    l_s += rs;
    unsigned bw[4][4];
#pragma unroll
    for (int kt32 = 0; kt32 < 2; kt32++)
#pragma unroll
      for (int tau = 0; tau < 2; tau++)
#pragma unroll
        for (int b2 = 0; b2 < 2; b2++) {
          unsigned Y = pk2(p[kt32][4 * (2 * tau) + 2 * b2],     p[kt32][4 * (2 * tau) + 2 * b2 + 1]);
          unsigned X = pk2(p[kt32][4 * (2 * tau + 1) + 2 * b2], p[kt32][4 * (2 * tau + 1) + 2 * b2 + 1]);
          u32x2 r2 = __builtin_amdgcn_permlane32_swap(Y, X, false, false);
          int tt = kt32 * 2 + tau;
          bw[tt][b2]     = r2[0];
          bw[tt][b2 + 2] = r2[1];
        }
    f16x8 pf[4];
#pragma unroll
    for (int tt = 0; tt < 4; tt++) {
      union { unsigned w[4]; f16x8 v; } u;
#pragma unroll
      for (int w = 0; w < 4; w++) u.w[w] = bw[tt][w];
      pf[tt] = u.v;
    }
#pragma unroll
    for (int d2 = 0; d2 < 2; d2++) {
      int row = d2 * 32 + q32;
      __builtin_amdgcn_s_setprio(1);
#pragma unroll
      for (int tt = 0; tt < 4; tt++) {
        f16x8 vf = *(const f16x8*)((const char*)lv + row * 128 + ((tt * 32 + hh * 16) ^ ((row & 7) << 4)));
        oacc[d2] = __builtin_amdgcn_mfma_f32_32x32x16_f16(vf, pf[tt], oacc[d2], 0, 0, 0);
      }
      __builtin_amdgcn_s_setprio(0);
    }
  };

  // 2 tiles per barrier interval, 4-buffer rotation:
  // interval i: barrier (drains stages of tiles 2i,2i+1 issued last interval;
  // all waves done with buffers being overwritten) -> stage 2i+2,2i+3 -> compute 2i,2i+1.
  f32x16 s[2], s2[2];
  STAGE(0, 0);
  STAGE(1, 1);
  for (int kt = 0; kt < 32; kt += 2) {
    __syncthreads();
    if (kt + 2 < 32) STAGE(kt + 2, (kt + 2) & 3);
    if (kt + 3 < 32) STAGE(kt + 3, (kt + 3) & 3);
    QK(kt & 3, s);
    SMPV(kt & 3, s);
    QK((kt + 1) & 3, s2);
    SMPV((kt + 1) & 3, s2);
  }

  // ---- epilogue: per-wave transpose in aliased LDS, coalesced write ----
  __syncthreads();                               // all staging reads done; safe to alias
  unsigned* epi = (unsigned*)smem_raw + wave * (32 * 36);
  float inv = 1.0f / l_s;
#pragma unroll
  for (int d2 = 0; d2 < 2; d2++)
#pragma unroll
    for (int aa = 0; aa < 4; aa++)
#pragma unroll
      for (int b2 = 0; b2 < 2; b2++) {
        int r0 = 4 * aa + 2 * b2;
        epi[q32 * 36 + d2 * 16 + 4 * aa + 2 * hh + b2] =
            pk2(oacc[d2][r0] * inv, oacc[d2][r0 + 1] * inv);
      }
  // wave-private write->read; compiler orders via lgkmcnt
  {
    int q2 = lane >> 1, part = lane & 1;
    const unsigned* src = (const unsigned*)smem_raw + wave * (32 * 36) + q2 * 36 + part * 16;
    u16* dst = AO + (size_t)(b * SS + qb + wave * 32 + q2) * NE + h * HD + part * 32;
#pragma unroll
    for (int u = 0; u < 4; u++)
      *(u32x4*)(dst + u * 8) = *(const u32x4*)(src + u * 4);
  }
}

extern "C" void kernel_launch(void* const* d_in, const int* in_sizes, int n_in,
                              void* d_out, int out_size, void* d_ws, size_t ws_size,
                              hipStream_t stream) {
  const float* x  = (const float*)d_in[0];
  const float* Wq = (const float*)d_in[1]; const float* bq = (const float*)d_in[2];
  const float* Wk = (const float*)d_in[3]; const float* bk = (const float*)d_in[4];
  const float* Wv = (const float*)d_in[5]; const float* bv = (const float*)d_in[6];
  const float* Wo = (const float*)d_in[7]; const float* bo = (const float*)d_in[8];

  u16* xb  = (u16*)d_ws;                       // [8192][1024]
  u16* WT  = xb  + (size_t)MR * NE;            // 4 x [1024][1024]
  u16* Qb  = WT  + (size_t)4 * NE * NE;        // [8192][1024]
  u16* Kb  = Qb  + (size_t)MR * NE;            // [8192][1024]
  u16* VTb = Kb  + (size_t)MR * NE;            // [B][H][D][S]
  u16* AOb = xb;                               // reuse xb after projections

  k_cvt_x<<<dim3(MR * NE / (256 * 8)), 256, 0, stream>>>(x, xb);
  k_wt<<<dim3(16, 16, 4), 256, 0, stream>>>(Wq, Wk, Wv, Wo, WT);

  dim3 gg(MR / 128, NE / 128);
  k_gemm<0><<<gg, 256, 0, stream>>>(xb, WT + 0 * (size_t)NE * NE, bq, Qb);
  k_gemm<0><<<gg, 256, 0, stream>>>(xb, WT + 1 * (size_t)NE * NE, bk, Kb);
  k_gemm<1><<<gg, 256, 0, stream>>>(xb, WT + 2 * (size_t)NE * NE, bv, VTb);

  k_attn<<<dim3(256), 1024, 0, stream>>>(Qb, Kb, VTb, AOb);

  k_gemm<2><<<gg, 256, 0, stream>>>(AOb, WT + 3 * (size_t)NE * NE, bo, (float*)d_out);
}

// Round 25
// 205.048 us; speedup vs baseline: 1.0289x; 1.0289x over previous
//
#include <hip/hip_runtime.h>
#include <hip/hip_bf16.h>

#define DEVI static __device__ __forceinline__

typedef __attribute__((ext_vector_type(8))) _Float16 f16x8;
typedef __attribute__((ext_vector_type(2))) __fp16 fp16v2;   // cvt_pkrtz return type
typedef __attribute__((ext_vector_type(4))) float f32x4;
typedef __attribute__((ext_vector_type(16))) float f32x16;
typedef __attribute__((ext_vector_type(8))) unsigned short u16x8;
typedef __attribute__((ext_vector_type(4))) unsigned int u32x4;
typedef __attribute__((ext_vector_type(2))) unsigned int u32x2;
typedef unsigned short u16;

constexpr int NE = 1024;   // n_embd
constexpr int NH = 16;     // heads
constexpr int HD = 64;     // head dim
constexpr int SB = 4;      // batch
constexpr int SS = 2048;   // seq
constexpr int MR = SB * SS; // 8192 rows

DEVI u16 f2h(float f) {
  union { _Float16 h; u16 u; } x;
  x.h = (_Float16)f;
  return x.u;
}

DEVI unsigned pk2(float lo, float hi) {
  union { fp16v2 h2; unsigned u; } cv;
  cv.h2 = __builtin_amdgcn_cvt_pkrtz(lo, hi);
  return cv.u;
}

DEVI void gload_lds16(const void* g, void* l) {
  __builtin_amdgcn_global_load_lds(
      (const __attribute__((address_space(1))) unsigned int*)g,
      (__attribute__((address_space(3))) unsigned int*)l, 16, 0, 0);
}

// ---------------- x fp32 -> fp16 ----------------
__global__ void k_cvt_x(const float* __restrict__ x, u16* __restrict__ xb) {
  size_t i = (size_t)blockIdx.x * 256 + threadIdx.x;
  const f32x4* s4 = (const f32x4*)x;
  f32x4 a = s4[2 * i], c = s4[2 * i + 1];
  u16x8 o;
  o[0] = f2h(a[0]); o[1] = f2h(a[1]); o[2] = f2h(a[2]); o[3] = f2h(a[3]);
  o[4] = f2h(c[0]); o[5] = f2h(c[1]); o[6] = f2h(c[2]); o[7] = f2h(c[3]);
  ((u16x8*)xb)[i] = o;
}

// ---------------- W [K][N] fp32 -> W^T [N][K] fp16 (4 weights) ----------------
__global__ void k_wt(const float* __restrict__ W0, const float* __restrict__ W1,
                     const float* __restrict__ W2, const float* __restrict__ W3,
                     u16* __restrict__ WT) {
  __shared__ float tile[64][65];
  const float* W = (blockIdx.z == 0) ? W0 : (blockIdx.z == 1) ? W1 : (blockIdx.z == 2) ? W2 : W3;
  u16* T = WT + (size_t)blockIdx.z * NE * NE;
  int tid = threadIdx.x, c = tid & 63, rr = tid >> 6;
  int ti = blockIdx.y * 64, tj = blockIdx.x * 64;
#pragma unroll
  for (int p = 0; p < 16; p++) {
    int r = p * 4 + rr;
    tile[r][c] = W[(size_t)(ti + r) * NE + tj + c];
  }
  __syncthreads();
#pragma unroll
  for (int p = 0; p < 16; p++) {
    int r = p * 4 + rr;
    T[(size_t)(tj + r) * NE + ti + c] = f2h(tile[c][r]);
  }
}

// ---------------- GEMM: C[M][1024] = A[M][1024] @ (BT[1024][1024])^T + bias ----------------
template <int MODE>
__global__ __launch_bounds__(256) void k_gemm(const u16* __restrict__ A,
                                              const u16* __restrict__ BT,
                                              const float* __restrict__ bias,
                                              void* __restrict__ outp) {
  __shared__ __align__(16) u16 lA[128 * 64];
  __shared__ __align__(16) u16 lB[128 * 64];
  const int tid = threadIdx.x;
  const int wave = tid >> 6, lane = tid & 63;
  const int wr = wave >> 1, wc = wave & 1;
  const int fr = lane & 15, fg = lane >> 4;
  const int srow = lane >> 3;
  const int scol = ((lane & 7) ^ srow) * 8;
  const int mb = blockIdx.x, nb = blockIdx.y;
  f32x4 acc[4][4] = {};
  for (int kt = 0; kt < NE / 64; ++kt) {
#pragma unroll
    for (int p = 0; p < 4; p++) {
      int rb = wave * 32 + p * 8;
      gload_lds16(A + (size_t)(mb * 128 + rb + srow) * NE + kt * 64 + scol, lA + rb * 64);
      gload_lds16(BT + (size_t)(nb * 128 + rb + srow) * NE + kt * 64 + scol, lB + rb * 64);
    }
    __syncthreads();
#pragma unroll
    for (int kd = 0; kd < 2; ++kd) {
      f16x8 af[4], bg[4];
#pragma unroll
      for (int mi = 0; mi < 4; mi++) {
        int row = wr * 64 + mi * 16 + fr;
        af[mi] = *(const f16x8*)((const char*)lA + row * 128 + ((kd * 64 + fg * 16) ^ ((row & 7) << 4)));
      }
#pragma unroll
      for (int nj = 0; nj < 4; nj++) {
        int row = wc * 64 + nj * 16 + fr;
        bg[nj] = *(const f16x8*)((const char*)lB + row * 128 + ((kd * 64 + fg * 16) ^ ((row & 7) << 4)));
      }
#pragma unroll
      for (int mi = 0; mi < 4; mi++)
#pragma unroll
        for (int nj = 0; nj < 4; nj++)
          acc[mi][nj] = __builtin_amdgcn_mfma_f32_16x16x32_f16(af[mi], bg[nj], acc[mi][nj], 0, 0, 0);
    }
    __syncthreads();
  }
  float bv[4];
#pragma unroll
  for (int nj = 0; nj < 4; nj++) bv[nj] = bias[nb * 128 + wc * 64 + nj * 16 + fr];
#pragma unroll
  for (int mi = 0; mi < 4; mi++)
#pragma unroll
    for (int nj = 0; nj < 4; nj++)
#pragma unroll
      for (int r = 0; r < 4; r++) {
        int row = mb * 128 + wr * 64 + mi * 16 + fg * 4 + r;
        int col = nb * 128 + wc * 64 + nj * 16 + fr;
        float v = acc[mi][nj][r] + bv[nj];
        if constexpr (MODE == 2) {
          ((float*)outp)[(size_t)row * NE + col] = v;
        } else if constexpr (MODE == 0) {
          ((u16*)outp)[(size_t)row * NE + col] = f2h(v);
        } else {
          int b = row >> 11, s = row & (SS - 1);
          int h = col >> 6, d = col & 63;
          ((u16*)outp)[(((size_t)(b * NH + h) * HD + d) << 11) | (size_t)s] = f2h(v);
        }
      }
}

// ---------------- flash attention: 16-wave blocks (1 block/CU -> 16 waves/CU) ----------------
// grid 256 (XCD-swizzled), 1024 threads (16 waves x 32 q-rows = 512 q-rows/block).
// Q,K: [B][S][H*D] fp16. VT: [B][H][D][S] fp16. AO: [B][S][H*D] fp16.
__global__ __launch_bounds__(1024) void k_attn(const u16* __restrict__ Q, const u16* __restrict__ K,
                                               const u16* __restrict__ VT, u16* __restrict__ AO) {
  // staging (32 KB) and epilogue (16 x 4.6 KB = 72 KB) alias; epilogue used only after the loop.
  __shared__ __align__(16) char smem_raw[73728];
  u16* smem = (u16*)smem_raw;                    // [K0|K1|V0|V1], each 64x64 fp16
  const int tid = threadIdx.x, wave = tid >> 6, lane = tid & 63;
  const int q32 = lane & 31, hh = lane >> 5;
  const int srow = lane >> 3;
  const int scol = ((lane & 7) ^ srow) * 8;
  // XCD-aware decode: 4 q-blocks (512 rows each) of one (b,h) stay on one XCD
  const int bid = blockIdx.x;
  const int xcd = bid & 7, idx = bid >> 3;       // idx in [0,32)
  const int g = xcd * 8 + (idx >> 2);            // (b,h) group in [0,64)
  const int qb = (idx & 3) * 512;
  const int b = g >> 4, h = g & 15;
  const u16* Kg = K + (size_t)(b * SS) * NE + h * HD;
  const u16* Vg = VT + (size_t)(b * NH + h) * HD * SS;
  const u16* Qp = Q + (size_t)(b * SS + qb + wave * 32 + q32) * NE + h * HD;
  f16x8 qf[4];
#pragma unroll
  for (int m = 0; m < 4; m++) qf[m] = *(const f16x8*)(Qp + m * 16 + hh * 8);
  f32x16 oacc[2] = {};
  float m_s = -1e30f, l_s = 0.f;
  const float SC = 8.0f * 1.44269504088896340736f;

  // 16 waves split the staging: waves 0-7 stage K rows [w*8,w*8+8), waves 8-15 stage V
  auto STAGE = [&](int kt2, int bufi) {
    if (wave < 8) {
      u16* lk = smem + bufi * 4096;
      int rb = wave * 8;
      gload_lds16(Kg + (size_t)(kt2 * 64 + rb + srow) * NE + scol, lk + rb * 64);
    } else {
      u16* lv = smem + 8192 + bufi * 4096;
      int rb = (wave - 8) * 8;
      gload_lds16(Vg + (size_t)(rb + srow) * SS + kt2 * 64 + scol, lv + rb * 64);
    }
  };

  auto QK = [&](int bufi, f32x16* s) {
    const u16* lk = smem + bufi * 4096;
#pragma unroll
    for (int kt32 = 0; kt32 < 2; kt32++) {
      f32x16 z = {};
      int row = kt32 * 32 + q32;
      __builtin_amdgcn_s_setprio(1);
#pragma unroll
      for (int m = 0; m < 4; m++) {
        f16x8 kf = *(const f16x8*)((const char*)lk + row * 128 + ((m * 32 + hh * 16) ^ ((row & 7) << 4)));
        z = __builtin_amdgcn_mfma_f32_32x32x16_f16(kf, qf[m], z, 0, 0, 0);
      }
      __builtin_amdgcn_s_setprio(0);
      s[kt32] = z;
    }
  };

  auto SMPV = [&](int bufiV, f32x16* s) {
    const u16* lv = smem + 8192 + bufiV * 4096;
    float a[16];
#pragma unroll
    for (int r = 0; r < 16; r++) a[r] = fmaxf(s[0][r], s[1][r]);
#pragma unroll
    for (int st = 8; st > 0; st >>= 1)
#pragma unroll
      for (int r = 0; r < st; r++) a[r] = fmaxf(a[r], a[r + st]);
    float mx = a[0] * SC;
    mx = fmaxf(mx, __shfl_xor(mx, 32));
    float mo = m_s, mu = mo;
    if (!__all(mx <= mo + 8.f)) {
      float nm = fmaxf(mo, mx);
      float fs = __builtin_amdgcn_exp2f(mo - nm);
      m_s = nm; mu = nm; l_s *= fs;
#pragma unroll
      for (int d2 = 0; d2 < 2; d2++)
#pragma unroll
        for (int r = 0; r < 16; r++) oacc[d2][r] *= fs;
    }
    float p[2][16];
#pragma unroll
    for (int kt32 = 0; kt32 < 2; kt32++)
#pragma unroll
      for (int r = 0; r < 16; r++)
        p[kt32][r] = __builtin_amdgcn_exp2f(s[kt32][r] * SC - mu);
    float t[16];
#pragma unroll
    for (int r = 0; r < 16; r++) t[r] = p[0][r] + p[1][r];
#pragma unroll
    for (int st = 8; st > 0; st >>= 1)
#pragma unroll
      for (int r = 0; r < st; r++) t[r] += t[r + st];
    float rs = t[0];
    rs += __shfl_xor(rs, 32);
    l_s += rs;
    unsigned bw[4][4];
#pragma unroll
    for (int kt32 = 0; kt32 < 2; kt32++)
#pragma unroll
      for (int tau = 0; tau < 2; tau++)
#pragma unroll
        for (int b2 = 0; b2 < 2; b2++) {
          unsigned Y = pk2(p[kt32][4 * (2 * tau) + 2 * b2],     p[kt32][4 * (2 * tau) + 2 * b2 + 1]);
          unsigned X = pk2(p[kt32][4 * (2 * tau + 1) + 2 * b2], p[kt32][4 * (2 * tau + 1) + 2 * b2 + 1]);
          u32x2 r2 = __builtin_amdgcn_permlane32_swap(Y, X, false, false);
          int tt = kt32 * 2 + tau;
          bw[tt][b2]     = r2[0];
          bw[tt][b2 + 2] = r2[1];
        }
    f16x8 pf[4];
#pragma unroll
    for (int tt = 0; tt < 4; tt++) {
      union { unsigned w[4]; f16x8 v; } u;
#pragma unroll
      for (int w = 0; w < 4; w++) u.w[w] = bw[tt][w];
      pf[tt] = u.v;
    }
#pragma unroll
    for (int d2 = 0; d2 < 2; d2++) {
      int row = d2 * 32 + q32;
      __builtin_amdgcn_s_setprio(1);
#pragma unroll
      for (int tt = 0; tt < 4; tt++) {
        f16x8 vf = *(const f16x8*)((const char*)lv + row * 128 + ((tt * 32 + hh * 16) ^ ((row & 7) << 4)));
        oacc[d2] = __builtin_amdgcn_mfma_f32_32x32x16_f16(vf, pf[tt], oacc[d2], 0, 0, 0);
      }
      __builtin_amdgcn_s_setprio(0);
    }
  };

  // proven 2-buf loop (R10/R15/R19 structure), staging amortized over 16 waves
  f32x16 s[2];
  STAGE(0, 0);
  for (int kt = 0; kt < 32; ++kt) {
    const int cur = kt & 1;
    __syncthreads();
    if (kt + 1 < 32) STAGE(kt + 1, cur ^ 1);
    QK(cur, s);
    SMPV(cur, s);
  }

  // ---- epilogue: per-wave transpose in aliased LDS, coalesced write ----
  __syncthreads();                               // all staging reads done; safe to alias
  unsigned* epi = (unsigned*)smem_raw + wave * (32 * 36);
  float inv = 1.0f / l_s;
#pragma unroll
  for (int d2 = 0; d2 < 2; d2++)
#pragma unroll
    for (int aa = 0; aa < 4; aa++)
#pragma unroll
      for (int b2 = 0; b2 < 2; b2++) {
        int r0 = 4 * aa + 2 * b2;
        epi[q32 * 36 + d2 * 16 + 4 * aa + 2 * hh + b2] =
            pk2(oacc[d2][r0] * inv, oacc[d2][r0 + 1] * inv);
      }
  // wave-private write->read; compiler orders via lgkmcnt
  {
    int q2 = lane >> 1, part = lane & 1;
    const unsigned* src = (const unsigned*)smem_raw + wave * (32 * 36) + q2 * 36 + part * 16;
    u16* dst = AO + (size_t)(b * SS + qb + wave * 32 + q2) * NE + h * HD + part * 32;
#pragma unroll
    for (int u = 0; u < 4; u++)
      *(u32x4*)(dst + u * 8) = *(const u32x4*)(src + u * 4);
  }
}

extern "C" void kernel_launch(void* const* d_in, const int* in_sizes, int n_in,
                              void* d_out, int out_size, void* d_ws, size_t ws_size,
                              hipStream_t stream) {
  const float* x  = (const float*)d_in[0];
  const float* Wq = (const float*)d_in[1]; const float* bq = (const float*)d_in[2];
  const float* Wk = (const float*)d_in[3]; const float* bk = (const float*)d_in[4];
  const float* Wv = (const float*)d_in[5]; const float* bv = (const float*)d_in[6];
  const float* Wo = (const float*)d_in[7]; const float* bo = (const float*)d_in[8];

  u16* xb  = (u16*)d_ws;                       // [8192][1024]
  u16* WT  = xb  + (size_t)MR * NE;            // 4 x [1024][1024]
  u16* Qb  = WT  + (size_t)4 * NE * NE;        // [8192][1024]
  u16* Kb  = Qb  + (size_t)MR * NE;            // [8192][1024]
  u16* VTb = Kb  + (size_t)MR * NE;            // [B][H][D][S]
  u16* AOb = xb;                               // reuse xb after projections

  k_cvt_x<<<dim3(MR * NE / (256 * 8)), 256, 0, stream>>>(x, xb);
  k_wt<<<dim3(16, 16, 4), 256, 0, stream>>>(Wq, Wk, Wv, Wo, WT);

  dim3 gg(MR / 128, NE / 128);
  k_gemm<0><<<gg, 256, 0, stream>>>(xb, WT + 0 * (size_t)NE * NE, bq, Qb);
  k_gemm<0><<<gg, 256, 0, stream>>>(xb, WT + 1 * (size_t)NE * NE, bk, Kb);
  k_gemm<1><<<gg, 256, 0, stream>>>(xb, WT + 2 * (size_t)NE * NE, bv, VTb);

  k_attn<<<dim3(256), 1024, 0, stream>>>(Qb, Kb, VTb, AOb);

  k_gemm<2><<<gg, 256, 0, stream>>>(AOb, WT + 3 * (size_t)NE * NE, bo, (float*)d_out);
}